// Round 1
// baseline (1439.049 us; speedup 1.0000x reference)
//
#include <hip/hip_runtime.h>
#include <math.h>

#define NB 4
#define P 2048
#define D 64
#define EPS 0.1f
#define INV_EPS 10.0f
#define MAX_ITER 50

// ---------------------------------------------------------------------------
// build_c: C[n][i][j] = sum_d (x[n][i][d]-y[n][j][d])^2, also writes CT (C^T)
// grid (32 j-tiles, 32 i-tiles, 4 batches), 256 threads, 64x64 tile, 4x4/thread
// ---------------------------------------------------------------------------
__global__ __launch_bounds__(256) void build_c(const float* __restrict__ x,
                                               const float* __restrict__ y,
                                               float* __restrict__ C,
                                               float* __restrict__ CT) {
  __shared__ float xs[D][68];  // [d][i-local], pad 68 to dodge bank conflicts
  __shared__ float ys[D][68];  // [d][j-local]
  const int n = blockIdx.z;
  const int i0 = blockIdx.y * 64, j0 = blockIdx.x * 64;
  const int t = threadIdx.x;
  const int lr = t >> 4, c4 = (t & 15) * 4;
  const size_t xb = (size_t)n * P * D;
  // load 64 rows x 64 dims of x and y, transposed into LDS
  for (int rr = lr; rr < 64; rr += 16) {
    float4 xv = *(const float4*)(x + xb + (size_t)(i0 + rr) * D + c4);
    float4 yv = *(const float4*)(y + xb + (size_t)(j0 + rr) * D + c4);
    xs[c4 + 0][rr] = xv.x; xs[c4 + 1][rr] = xv.y;
    xs[c4 + 2][rr] = xv.z; xs[c4 + 3][rr] = xv.w;
    ys[c4 + 0][rr] = yv.x; ys[c4 + 1][rr] = yv.y;
    ys[c4 + 2][rr] = yv.z; ys[c4 + 3][rr] = yv.w;
  }
  __syncthreads();
  const int ty = t >> 4, tx = t & 15;
  float acc[4][4];
#pragma unroll
  for (int e = 0; e < 4; ++e)
#pragma unroll
    for (int f = 0; f < 4; ++f) acc[e][f] = 0.f;
#pragma unroll 4
  for (int d = 0; d < D; ++d) {
    float4 a4 = *(const float4*)&xs[d][4 * ty];
    float4 b4 = *(const float4*)&ys[d][4 * tx];
    float av[4] = {a4.x, a4.y, a4.z, a4.w};
    float bv[4] = {b4.x, b4.y, b4.z, b4.w};
#pragma unroll
    for (int e = 0; e < 4; ++e)
#pragma unroll
      for (int f = 0; f < 4; ++f) {
        float df = av[e] - bv[f];
        acc[e][f] = fmaf(df, df, acc[e][f]);
      }
  }
  const size_t cb = (size_t)n * P * P;
#pragma unroll
  for (int e = 0; e < 4; ++e) {
    float4 v4 = make_float4(acc[e][0], acc[e][1], acc[e][2], acc[e][3]);
    *(float4*)(C + cb + (size_t)(i0 + 4 * ty + e) * P + (j0 + 4 * tx)) = v4;
  }
#pragma unroll
  for (int f = 0; f < 4; ++f) {
    float4 v4 = make_float4(acc[0][f], acc[1][f], acc[2][f], acc[3][f]);
    *(float4*)(CT + cb + (size_t)(j0 + 4 * tx + f) * P + (i0 + 4 * ty)) = v4;
  }
}

// ---------------------------------------------------------------------------
// lse_pass: out[b] = EPS * (log_w - LSE_c((w[c] - M[b][c]) / EPS))
// one block per (n, row): 8192 blocks x 256 threads, 8 elems/thread
// u-update: M=C,  w=v, out=u     v-update: M=CT, w=u, out=v
// ---------------------------------------------------------------------------
__global__ __launch_bounds__(256) void lse_pass(const float* __restrict__ M,
                                                const float* __restrict__ w,
                                                float* __restrict__ out,
                                                float log_w) {
  __shared__ float red[8];
  const int b = blockIdx.x;
  const int n = b >> 11;
  const int t = threadIdx.x;
  const float4* row = (const float4*)(M + (size_t)b * P);
  const float4* wv = (const float4*)(w + (size_t)n * P);
  float4 c0 = row[t], c1 = row[t + 256];
  float4 w0 = wv[t], w1 = wv[t + 256];
  float a[8];
  a[0] = (w0.x - c0.x) * INV_EPS;
  a[1] = (w0.y - c0.y) * INV_EPS;
  a[2] = (w0.z - c0.z) * INV_EPS;
  a[3] = (w0.w - c0.w) * INV_EPS;
  a[4] = (w1.x - c1.x) * INV_EPS;
  a[5] = (w1.y - c1.y) * INV_EPS;
  a[6] = (w1.z - c1.z) * INV_EPS;
  a[7] = (w1.w - c1.w) * INV_EPS;
  float mx = a[0];
#pragma unroll
  for (int k = 1; k < 8; ++k) mx = fmaxf(mx, a[k]);
#pragma unroll
  for (int o = 32; o > 0; o >>= 1) mx = fmaxf(mx, __shfl_xor(mx, o));
  if ((t & 63) == 0) red[t >> 6] = mx;
  __syncthreads();
  mx = fmaxf(fmaxf(red[0], red[1]), fmaxf(red[2], red[3]));
  float s = 0.f;
#pragma unroll
  for (int k = 0; k < 8; ++k) s += __expf(a[k] - mx);
#pragma unroll
  for (int o = 32; o > 0; o >>= 1) s += __shfl_xor(s, o);
  if ((t & 63) == 0) red[4 + (t >> 6)] = s;
  __syncthreads();
  if (t == 0) {
    float S = red[4] + red[5] + red[6] + red[7];
    out[b] = EPS * (log_w - (mx + __logf(S)));
  }
}

// ---------------------------------------------------------------------------
// final_pass: pi = exp((-C + u_i + v_j)/EPS), cost[n] += sum(pi*C)
// one block per (n, row). Overwrites the CT scratch (pi slot) with pi.
// ---------------------------------------------------------------------------
__global__ __launch_bounds__(256) void final_pass(const float* __restrict__ C,
                                                  const float* __restrict__ u,
                                                  const float* __restrict__ v,
                                                  float* __restrict__ pi,
                                                  float* __restrict__ cost) {
  __shared__ float red[4];
  const int b = blockIdx.x;
  const int n = b >> 11;
  const int t = threadIdx.x;
  const float ui = u[b];
  const float4* row = (const float4*)(C + (size_t)b * P);
  const float4* vv = (const float4*)(v + (size_t)n * P);
  float4* prow = (float4*)(pi + (size_t)b * P);
  float local = 0.f;
#pragma unroll
  for (int h = 0; h < 2; ++h) {
    float4 c = row[t + 256 * h];
    float4 vw = vv[t + 256 * h];
    float4 p;
    p.x = __expf((ui + vw.x - c.x) * INV_EPS);
    p.y = __expf((ui + vw.y - c.y) * INV_EPS);
    p.z = __expf((ui + vw.z - c.z) * INV_EPS);
    p.w = __expf((ui + vw.w - c.w) * INV_EPS);
    prow[t + 256 * h] = p;
    local += p.x * c.x + p.y * c.y + p.z * c.z + p.w * c.w;
  }
#pragma unroll
  for (int o = 32; o > 0; o >>= 1) local += __shfl_xor(local, o);
  if ((t & 63) == 0) red[t >> 6] = local;
  __syncthreads();
  if (t == 0) {
    float S = red[0] + red[1] + red[2] + red[3];
    atomicAdd(cost + n, S);
  }
}

extern "C" void kernel_launch(void* const* d_in, const int* in_sizes, int n_in,
                              void* d_out, int out_size, void* d_ws, size_t ws_size,
                              hipStream_t stream) {
  const float* x = (const float*)d_in[0];
  const float* y = (const float*)d_in[1];
  float* cost = (float*)d_out;                 // 4 floats
  float* pi = cost + 4;                        // 4*2048*2048
  float* C = pi + (size_t)NB * P * P;          // 4*2048*2048
  float* CT = pi;  // reuse pi output slot as C^T scratch until final_pass
  float* u = (float*)d_ws;                     // 4*2048
  float* v = u + NB * P;                       // 4*2048

  hipMemsetAsync(cost, 0, NB * sizeof(float), stream);
  hipMemsetAsync(v, 0, NB * P * sizeof(float), stream);

  const float log_mu = logf(1.0f / (float)P + 1e-8f);  // == log_nu

  build_c<<<dim3(32, 32, 4), 256, 0, stream>>>(x, y, C, CT);

  for (int it = 0; it < MAX_ITER; ++it) {
    lse_pass<<<NB * P, 256, 0, stream>>>(C, v, u, log_mu);   // u-update
    lse_pass<<<NB * P, 256, 0, stream>>>(CT, u, v, log_mu);  // v-update
  }
  final_pass<<<NB * P, 256, 0, stream>>>(C, u, v, pi, cost);
}